// Round 6
// baseline (37203.094 us; speedup 1.0000x reference)
//
#include <hip/hip_runtime.h>
#include <stdint.h>
#include <math.h>

#define TSTEPS 256
#define BATCH  256
#define OBS_D  512
#define FEATD  512
#define NACT   15
#define HDIM   528
#define HB     (HDIM*BATCH)   /* 135168 */

/* ---- compact ws layout (total 5,774,528 bytes) ----
   float idx:
   [0)        nd   f32 [T][B]              65536 floats
   [65536)    flag int (16 floats reserved)
   byte 262208: alw f64 x 13200            -> ends byte 367808
   float idx 91952: ST f32:
     XT ring [4][HDIM][BATCH]
     H0 [2][HDIM][BATCH], H1 [2][HDIM][BATCH]
     C0 [HDIM][BATCH],   C1 [HDIM][BATCH]  */
#define OFF_ND    0
#define OFF_FLAG  65536
#define ALW_BYTES 262208
#define SB        91952            /* ST float base */
#define FXT       (SB)
#define FH0       (FXT + 4*HB)
#define FH1       (FH0 + 2*HB)
#define FC0       (FH1 + 2*HB)
#define FC1       (FC0 + HB)
#define FST_END   (FC1 + HB)       /* 1443632 floats = 5774528 B */

/* ALW double offsets */
#define DBS0   0
#define DBS1   2112
#define DBENC  4224
#define DHW    4736
#define DHB    13184
#define DALW_N 13200

/* out float offsets */
#define OUT_POL   0
#define OUT_BASE  983040
#define OUT_ACT   1048576
#define OUT_H     1114112
#define OUT_C     1384448

__device__ __forceinline__ double sigd_(double x){ return 1.0/(1.0+exp(-x)); }

__device__ __forceinline__ uint32_t rotl32_(uint32_t x, uint32_t d){
  return (x<<d)|(x>>(32u-d));
}

/* JAX partitionable threefry, 32-bit path: (out0,out1)=threefry2x32(key=(0,1),
   ctr=(0,i)); bits = out0 ^ out1.  [VERIFIED: first-pass check passed in R5] */
__device__ double gumbel_for(uint32_t idx){
  uint32_t x0 = 0u, x1 = idx;
  const uint32_t k0 = 0u, k1 = 1u;
  const uint32_t ks[3] = {k0, k1, 0x1BD11BDAu ^ k0 ^ k1};
  x0 += ks[0]; x1 += ks[1];
  const uint32_t R0[4] = {13u,15u,26u,6u}, R1[4] = {17u,29u,16u,24u};
  #pragma unroll
  for (int g=0; g<5; ++g){
    const uint32_t* r = (g&1) ? R1 : R0;
    #pragma unroll
    for (int j=0;j<4;++j){ x0 += x1; x1 = rotl32_(x1, r[j]); x1 ^= x0; }
    x0 += ks[(g+1)%3];
    x1 += ks[(g+2)%3] + (uint32_t)(g+1);
  }
  const uint32_t bits = x0 ^ x1;
  float u = __uint_as_float((bits>>9) | 0x3f800000u) - 1.0f;
  const float TINY = 1.17549435e-38f;
  u = u * (1.0f - TINY) + TINY;
  u = fmaxf(TINY, u);
  return -log(-log((double)u));
}

__global__ void zero_kernel(float* __restrict__ p, int n){
  int i = blockIdx.x*256 + threadIdx.x;
  if (i < n) p[i] = 0.0f;
}

/* classify terminated[] packing: 0=bool bytes, 1=int32, 2=float32 */
__global__ void detect_term_kernel(const void* __restrict__ term, int* __restrict__ flag){
  __shared__ int s_nf, s_nb, s_ni;
  if (threadIdx.x==0){ s_nf=0; s_nb=0; s_ni=0; }
  __syncthreads();
  const uint8_t*  pb = (const uint8_t*)term;
  const uint32_t* pw = (const uint32_t*)term;
  int nf=0, nb=0, ni=0;
  for (int i=threadIdx.x; i<16384; i+=256){
    uint32_t v = pw[i];
    if (v == 0x3F800000u) nf++;
    if (v == 1u) ni++;
  }
  for (int o=threadIdx.x; o<65536; o+=256){
    if ((o&3) && pb[o]) nb++;
  }
  if (nf) atomicAdd(&s_nf, nf);
  if (nb) atomicAdd(&s_nb, nb);
  if (ni) atomicAdd(&s_ni, ni);
  __syncthreads();
  if (threadIdx.x==0){
    flag[0] = (s_nf>0) ? 2 : ((s_nb>0) ? 0 : ((s_ni>0) ? 1 : 0));
  }
}

__global__ void nd_kernel(const void* __restrict__ term, const int* __restrict__ flag,
                          float* __restrict__ nd){
  int i = blockIdx.x*256 + threadIdx.x;
  if (i >= TSTEPS*BATCH) return;
  int f = flag[0];
  bool done;
  if (f == 0)      done = ((const uint8_t*)term)[i] != 0;
  else if (f == 1) done = ((const int*)term)[i] != 0;
  else             done = ((const float*)term)[i] != 0.0f;
  nd[i] = done ? 0.0f : 1.0f;
}

/* biases + head weights -> f64 */
__global__ void prep_small_kernel(double* __restrict__ alw,
    const float* __restrict__ bih0, const float* __restrict__ bhh0,
    const float* __restrict__ bih1, const float* __restrict__ bhh1,
    const float* __restrict__ benc,
    const float* __restrict__ Wpol, const float* __restrict__ bpol,
    const float* __restrict__ Wbase, const float* __restrict__ bbase){
  int i = blockIdx.x*256 + threadIdx.x;
  if (i >= DALW_N) return;
  if (i < 2112)            alw[DBS0 + i] = (double)bih0[i] + (double)bhh0[i];
  else if (i < 4224)       { int j=i-2112; alw[DBS1 + j] = (double)bih1[j] + (double)bhh1[j]; }
  else if (i < 4736)       { int j=i-4224; alw[DBENC + j] = (double)benc[j]; }
  else if (i < 13184)      { int j=i-4736; int r=j/HDIM, k=j%HDIM;
                             alw[DHW + j] = (double)(r<NACT ? Wpol[r*HDIM+k] : Wbase[k]); }
  else                     { int j=i-13184; alw[DHB + j] = (double)(j<NACT ? bpol[j] : bbase[0]); }
}

/* One LSTM layer j-tile (8 gate cols), thread = batch row.
   f32 weights + f32 state, f64 accumulation. */
__device__ __forceinline__ void lstm_block(
    int jt, int step, const float* __restrict__ srcA, const float* __restrict__ srcB,
    const float* __restrict__ wih, const float* __restrict__ whh,
    const double* __restrict__ bsum,
    const float* __restrict__ nd, float* __restrict__ cbuf, float* __restrict__ hout,
    int b)
{
  const int j0 = jt*2;
  const double ndv = (double)nd[step*BATCH + b];
  double acc[8];
  const float* wA[8]; const float* wB[8];
  #pragma unroll
  for (int c=0;c<8;++c){
    const int col = (c>>1)*HDIM + j0 + (c&1);
    acc[c] = bsum[col];
    wA[c] = wih + (size_t)col*HDIM;
    wB[c] = whh + (size_t)col*HDIM;
  }
  const float* a = srcA + b;
  #pragma unroll 4
  for (int k=0;k<HDIM;++k){
    const double xv = (double)a[(size_t)k*BATCH];
    #pragma unroll
    for (int c=0;c<8;++c) acc[c] = fma((double)wA[c][k], xv, acc[c]);
  }
  const float* bb = srcB + b;
  #pragma unroll 4
  for (int k=0;k<HDIM;++k){
    const double hv = (double)bb[(size_t)k*BATCH] * ndv;
    #pragma unroll
    for (int c=0;c<8;++c) acc[c] = fma((double)wB[c][k], hv, acc[c]);
  }
  #pragma unroll
  for (int jj=0;jj<2;++jj){
    const double gi=acc[0+jj], gf=acc[2+jj], gg=acc[4+jj], go=acc[6+jj];
    const int idx=(j0+jj)*BATCH+b;
    const double cold = (double)cbuf[idx]*ndv;
    const double cn = sigd_(gf)*cold + sigd_(gi)*tanh(gg);
    const double hn = sigd_(go)*tanh(cn);
    cbuf[idx]=(float)cn; hout[idx]=(float)hn;
  }
}

/* Skewed pipeline: [0,264)=L0@t, [264,528)=L1@t-1, [528,592)=enc@t+2,
   592=enc extras @t+2, 593=head+sample @t-2 */
__global__ __launch_bounds__(256) void step_kernel(
  const float* __restrict__ obs, const int* __restrict__ lastAct,
  const float* __restrict__ reward,
  const float* __restrict__ wenc,
  const float* __restrict__ wih0, const float* __restrict__ whh0,
  const float* __restrict__ wih1, const float* __restrict__ whh1,
  float* __restrict__ ws, double* __restrict__ alw,
  float* __restrict__ out, int t)
{
  const int bid = blockIdx.x;
  const int b = threadIdx.x;
  float* nd = ws + OFF_ND;
  float* xT = ws + FXT;
  float* h0 = ws + FH0;
  float* h1 = ws + FH1;
  float* c0 = ws + FC0;
  float* c1 = ws + FC1;

  if (bid < 264) {                       /* layer 0 @ t */
    if (t < 0 || t > 255) return;
    lstm_block(bid, t,
               xT + (size_t)(t&3)*HB,
               h0 + (size_t)((t+1)&1)*HB,
               wih0, whh0, alw + DBS0, nd, c0,
               h0 + (size_t)(t&1)*HB, b);
  } else if (bid < 528) {                /* layer 1 @ t-1 */
    const int s = t - 1;
    if (s < 0 || s > 255) return;
    lstm_block(bid-264, s,
               h0 + (size_t)(s&1)*HB,
               h1 + (size_t)((s+1)&1)*HB,
               wih1, whh1, alw + DBS1, nd, c1,
               h1 + (size_t)(s&1)*HB, b);
  } else if (bid < 593) {                /* encoder @ t+2 */
    const int te = t + 2;
    if (te < 0 || te > 255) return;
    float* xs = xT + (size_t)(te&3)*HB;
    if (bid < 592) {
      const int e = bid - 528;
      const int f0 = e*8;
      double acc[8];
      const float* wrow[8];
      #pragma unroll
      for (int c=0;c<8;++c){ acc[c]=alw[DBENC+f0+c]; wrow[c]=wenc+(size_t)(f0+c)*OBS_D; }
      __shared__ float lx[32][257];
      const int r0 = threadIdx.x>>3;
      const int kk = (threadIdx.x&7)<<2;
      for (int kc=0; kc<OBS_D; kc+=32){
        __syncthreads();
        #pragma unroll
        for (int rr=0; rr<256; rr+=32){
          const float4 v = *(const float4*)(obs + ((size_t)te*BATCH + (r0+rr))*OBS_D + kc + kk);
          lx[kk+0][r0+rr]=v.x; lx[kk+1][r0+rr]=v.y; lx[kk+2][r0+rr]=v.z; lx[kk+3][r0+rr]=v.w;
        }
        __syncthreads();
        #pragma unroll 4
        for (int k2=0;k2<32;++k2){
          const double xv = (double)lx[k2][b];
          #pragma unroll
          for (int c=0;c<8;++c) acc[c] = fma(xv, (double)wrow[c][kc+k2], acc[c]);
        }
      }
      #pragma unroll
      for (int c=0;c<8;++c) xs[(size_t)(f0+c)*BATCH + b] = (float)fmax(acc[c], 0.0);
    } else {
      const float r = reward[te*BATCH + b];
      xs[(size_t)FEATD*BATCH + b] = fminf(fmaxf(r, -1.0f), 1.0f);
      const int la = lastAct[te*BATCH + b];
      #pragma unroll
      for (int a2=0; a2<NACT; ++a2)
        xs[(size_t)(FEATD+1+a2)*BATCH + b] = (a2==la) ? 1.0f : 0.0f;
    }
  } else {                               /* head + sampling @ t-2 */
    const int s = t - 2;
    if (s < 0 || s > 255) return;
    const float* hsrc = h1 + (size_t)(s&1)*HB;
    double acc[16];
    #pragma unroll
    for (int c=0;c<16;++c) acc[c]=alw[DHB+c];
    const float* hb = hsrc + b;
    #pragma unroll 4
    for (int k=0;k<HDIM;++k){
      const double hv = (double)hb[(size_t)k*BATCH];
      #pragma unroll
      for (int c=0;c<16;++c) acc[c] = fma(hv, alw[DHW + (size_t)c*HDIM + k], acc[c]);
    }
    const int row = s*BATCH + b;
    #pragma unroll
    for (int c=0;c<15;++c) out[OUT_POL + (size_t)row*NACT + c] = (float)acc[c];
    out[OUT_BASE + row] = (float)acc[15];
    double best = -1.0e300; int bi = 0;
    #pragma unroll
    for (int a2=0; a2<NACT; ++a2){
      const double v = acc[a2] + gumbel_for((uint32_t)(row*NACT + a2));
      if (v > best){ best = v; bi = a2; }
    }
    out[OUT_ACT + row] = (float)bi;
  }
}

__global__ void finalize_kernel(const float* __restrict__ ws, float* __restrict__ out){
  int i = blockIdx.x*256 + threadIdx.x;
  if (i >= 2*HB) return;
  const int l = i / HB;
  const int r = i % HB;
  const int bq = r / HDIM;
  const int j  = r % HDIM;
  const float* hf = ws + (l==0 ? FH0 : FH1) + HB;   /* step-255 parity = 1 */
  const float* cf = ws + (l==0 ? FC0 : FC1);
  out[OUT_H + i] = hf[(size_t)j*BATCH + bq];
  out[OUT_C + i] = cf[(size_t)j*BATCH + bq];
}

extern "C" void kernel_launch(void* const* d_in, const int* in_sizes, int n_in,
                              void* d_out, int out_size, void* d_ws, size_t ws_size,
                              hipStream_t stream) {
  const float* obs     = (const float*)d_in[0];
  const int*   lastAct = (const int*)  d_in[1];
  const float* reward  = (const float*)d_in[2];
  const void*  term    =               d_in[3];
  const float* Wenc    = (const float*)d_in[4];
  const float* benc    = (const float*)d_in[5];
  const float* wih0    = (const float*)d_in[6];
  const float* whh0    = (const float*)d_in[7];
  const float* bih0    = (const float*)d_in[8];
  const float* bhh0    = (const float*)d_in[9];
  const float* wih1    = (const float*)d_in[10];
  const float* whh1    = (const float*)d_in[11];
  const float* bih1    = (const float*)d_in[12];
  const float* bhh1    = (const float*)d_in[13];
  const float* Wpol    = (const float*)d_in[14];
  const float* bpol    = (const float*)d_in[15];
  const float* Wbase   = (const float*)d_in[16];
  const float* bbase   = (const float*)d_in[17];
  float*  ws   = (float*)d_ws;
  int*    flag = (int*)(ws + OFF_FLAG);
  double* alw  = (double*)((char*)d_ws + ALW_BYTES);
  float*  out  = (float*)d_out;

  /* zero h/c state (6*HB floats at FH0) every call */
  {
    const int nz = 6*HB;
    zero_kernel<<<(nz+255)/256, 256, 0, stream>>>(ws + FH0, nz);
  }
  detect_term_kernel<<<1, 256, 0, stream>>>(term, flag);
  nd_kernel<<<(TSTEPS*BATCH+255)/256, 256, 0, stream>>>(term, flag, ws + OFF_ND);
  prep_small_kernel<<<(DALW_N+255)/256, 256, 0, stream>>>(alw,
      bih0, bhh0, bih1, bhh1, benc, Wpol, bpol, Wbase, bbase);

  for (int t = -2; t <= 257; ++t) {
    step_kernel<<<594, 256, 0, stream>>>(
      obs, lastAct, reward,
      Wenc, wih0, whh0, wih1, whh1,
      ws, alw, out, t);
  }
  finalize_kernel<<<(2*HB+255)/256, 256, 0, stream>>>(ws, out);
}

// Round 7
// 22288.611 us; speedup vs baseline: 1.6692x; 1.6692x over previous
//
#include <hip/hip_runtime.h>
#include <stdint.h>
#include <math.h>

#define TSTEPS 256
#define BATCH  256
#define OBS_D  512
#define FEATD  512
#define NACT   15
#define HDIM   528
#define HB     (HDIM*BATCH)   /* 135168 */

/* ---- compact ws layout (total 5,774,528 bytes) ----
   [0)        nd   f32 [T][B]              65536 floats
   [65536)    flag int (16 floats reserved)
   byte 262208: alw f32 x 13200            -> ends byte 315008
   float idx 91952: ST f32:
     XT ring [4][HDIM][BATCH]
     H0 [2][HDIM][BATCH], H1 [2][HDIM][BATCH]
     C0 [HDIM][BATCH],   C1 [HDIM][BATCH]  */
#define OFF_ND    0
#define OFF_FLAG  65536
#define ALW_BYTES 262208
#define SB        91952
#define FXT       (SB)
#define FH0       (FXT + 4*HB)
#define FH1       (FH0 + 2*HB)
#define FC0       (FH1 + 2*HB)
#define FC1       (FC0 + HB)
#define FST_END   (FC1 + HB)

/* ALW float offsets */
#define DBS0   0
#define DBS1   2112
#define DBENC  4224
#define DHW    4736
#define DHB    13184
#define DALW_N 13200

/* out float offsets */
#define OUT_POL   0
#define OUT_BASE  983040
#define OUT_ACT   1048576
#define OUT_H     1114112
#define OUT_C     1384448

__device__ __forceinline__ float sigf_(float x){ return 1.0f/(1.0f+expf(-x)); }

__device__ __forceinline__ uint32_t rotl32_(uint32_t x, uint32_t d){
  return (x<<d)|(x>>(32u-d));
}

/* JAX partitionable threefry, 32-bit path: (out0,out1)=threefry2x32(key=(0,1),
   ctr=(0,i)); bits = out0 ^ out1.  [VERIFIED: R5/R6 passed] */
__device__ double gumbel_for(uint32_t idx){
  uint32_t x0 = 0u, x1 = idx;
  const uint32_t k0 = 0u, k1 = 1u;
  const uint32_t ks[3] = {k0, k1, 0x1BD11BDAu ^ k0 ^ k1};
  x0 += ks[0]; x1 += ks[1];
  const uint32_t R0[4] = {13u,15u,26u,6u}, R1[4] = {17u,29u,16u,24u};
  #pragma unroll
  for (int g=0; g<5; ++g){
    const uint32_t* r = (g&1) ? R1 : R0;
    #pragma unroll
    for (int j=0;j<4;++j){ x0 += x1; x1 = rotl32_(x1, r[j]); x1 ^= x0; }
    x0 += ks[(g+1)%3];
    x1 += ks[(g+2)%3] + (uint32_t)(g+1);
  }
  const uint32_t bits = x0 ^ x1;
  float u = __uint_as_float((bits>>9) | 0x3f800000u) - 1.0f;
  const float TINY = 1.17549435e-38f;
  u = u * (1.0f - TINY) + TINY;
  u = fmaxf(TINY, u);
  return -log(-log((double)u));
}

__global__ void zero_kernel(float* __restrict__ p, int n){
  int i = blockIdx.x*256 + threadIdx.x;
  if (i < n) p[i] = 0.0f;
}

/* classify terminated[] packing: 0=bool bytes, 1=int32, 2=float32 */
__global__ void detect_term_kernel(const void* __restrict__ term, int* __restrict__ flag){
  __shared__ int s_nf, s_nb, s_ni;
  if (threadIdx.x==0){ s_nf=0; s_nb=0; s_ni=0; }
  __syncthreads();
  const uint8_t*  pb = (const uint8_t*)term;
  const uint32_t* pw = (const uint32_t*)term;
  int nf=0, nb=0, ni=0;
  for (int i=threadIdx.x; i<16384; i+=256){
    uint32_t v = pw[i];
    if (v == 0x3F800000u) nf++;
    if (v == 1u) ni++;
  }
  for (int o=threadIdx.x; o<65536; o+=256){
    if ((o&3) && pb[o]) nb++;
  }
  if (nf) atomicAdd(&s_nf, nf);
  if (nb) atomicAdd(&s_nb, nb);
  if (ni) atomicAdd(&s_ni, ni);
  __syncthreads();
  if (threadIdx.x==0){
    flag[0] = (s_nf>0) ? 2 : ((s_nb>0) ? 0 : ((s_ni>0) ? 1 : 0));
  }
}

__global__ void nd_kernel(const void* __restrict__ term, const int* __restrict__ flag,
                          float* __restrict__ nd){
  int i = blockIdx.x*256 + threadIdx.x;
  if (i >= TSTEPS*BATCH) return;
  int f = flag[0];
  bool done;
  if (f == 0)      done = ((const uint8_t*)term)[i] != 0;
  else if (f == 1) done = ((const int*)term)[i] != 0;
  else             done = ((const float*)term)[i] != 0.0f;
  nd[i] = done ? 0.0f : 1.0f;
}

/* biases + head weights -> f32 staging */
__global__ void prep_small_kernel(float* __restrict__ alw,
    const float* __restrict__ bih0, const float* __restrict__ bhh0,
    const float* __restrict__ bih1, const float* __restrict__ bhh1,
    const float* __restrict__ benc,
    const float* __restrict__ Wpol, const float* __restrict__ bpol,
    const float* __restrict__ Wbase, const float* __restrict__ bbase){
  int i = blockIdx.x*256 + threadIdx.x;
  if (i >= DALW_N) return;
  if (i < 2112)            alw[DBS0 + i] = bih0[i] + bhh0[i];
  else if (i < 4224)       { int j=i-2112; alw[DBS1 + j] = bih1[j] + bhh1[j]; }
  else if (i < 4736)       { int j=i-4224; alw[DBENC + j] = benc[j]; }
  else if (i < 13184)      { int j=i-4736; int r=j/HDIM, k=j%HDIM;
                             alw[DHW + j] = (r<NACT ? Wpol[r*HDIM+k] : Wbase[k]); }
  else                     { int j=i-13184; alw[DHB + j] = (j<NACT ? bpol[j] : bbase[0]); }
}

/* One LSTM layer j-tile (8 gate cols), thread = batch row. Pure f32. */
__device__ __forceinline__ void lstm_block(
    int jt, int step, const float* __restrict__ srcA, const float* __restrict__ srcB,
    const float* __restrict__ wih, const float* __restrict__ whh,
    const float* __restrict__ bsum,
    const float* __restrict__ nd, float* __restrict__ cbuf, float* __restrict__ hout,
    int b)
{
  const int j0 = jt*2;
  const float ndv = nd[step*BATCH + b];
  float acc[8];
  const float* wA[8]; const float* wB[8];
  #pragma unroll
  for (int c=0;c<8;++c){
    const int col = (c>>1)*HDIM + j0 + (c&1);
    acc[c] = bsum[col];
    wA[c] = wih + (size_t)col*HDIM;
    wB[c] = whh + (size_t)col*HDIM;
  }
  const float* a = srcA + b;
  #pragma unroll 8
  for (int k=0;k<HDIM;++k){
    const float xv = a[(size_t)k*BATCH];
    #pragma unroll
    for (int c=0;c<8;++c) acc[c] = fmaf(wA[c][k], xv, acc[c]);
  }
  const float* bb = srcB + b;
  #pragma unroll 8
  for (int k=0;k<HDIM;++k){
    const float hv = bb[(size_t)k*BATCH] * ndv;
    #pragma unroll
    for (int c=0;c<8;++c) acc[c] = fmaf(wB[c][k], hv, acc[c]);
  }
  #pragma unroll
  for (int jj=0;jj<2;++jj){
    const float gi=acc[0+jj], gf=acc[2+jj], gg=acc[4+jj], go=acc[6+jj];
    const int idx=(j0+jj)*BATCH+b;
    const float cold = cbuf[idx]*ndv;
    const float cn = sigf_(gf)*cold + sigf_(gi)*tanhf(gg);
    const float hn = sigf_(go)*tanhf(cn);
    cbuf[idx]=cn; hout[idx]=hn;
  }
}

/* Skewed pipeline: [0,264)=L0@t, [264,528)=L1@t-1, [528,592)=enc@t+2,
   592=enc extras @t+2, 593=head+sample @t-2 */
__global__ __launch_bounds__(256) void step_kernel(
  const float* __restrict__ obs, const int* __restrict__ lastAct,
  const float* __restrict__ reward,
  const float* __restrict__ wenc,
  const float* __restrict__ wih0, const float* __restrict__ whh0,
  const float* __restrict__ wih1, const float* __restrict__ whh1,
  float* __restrict__ ws, float* __restrict__ alw,
  float* __restrict__ out, int t)
{
  const int bid = blockIdx.x;
  const int b = threadIdx.x;
  float* nd = ws + OFF_ND;
  float* xT = ws + FXT;
  float* h0 = ws + FH0;
  float* h1 = ws + FH1;
  float* c0 = ws + FC0;
  float* c1 = ws + FC1;

  if (bid < 264) {                       /* layer 0 @ t */
    if (t < 0 || t > 255) return;
    lstm_block(bid, t,
               xT + (size_t)(t&3)*HB,
               h0 + (size_t)((t+1)&1)*HB,
               wih0, whh0, alw + DBS0, nd, c0,
               h0 + (size_t)(t&1)*HB, b);
  } else if (bid < 528) {                /* layer 1 @ t-1 */
    const int s = t - 1;
    if (s < 0 || s > 255) return;
    lstm_block(bid-264, s,
               h0 + (size_t)(s&1)*HB,
               h1 + (size_t)((s+1)&1)*HB,
               wih1, whh1, alw + DBS1, nd, c1,
               h1 + (size_t)(s&1)*HB, b);
  } else if (bid < 593) {                /* encoder @ t+2 */
    const int te = t + 2;
    if (te < 0 || te > 255) return;
    float* xs = xT + (size_t)(te&3)*HB;
    if (bid < 592) {
      const int e = bid - 528;
      const int f0 = e*8;
      float acc[8];
      const float* wrow[8];
      #pragma unroll
      for (int c=0;c<8;++c){ acc[c]=alw[DBENC+f0+c]; wrow[c]=wenc+(size_t)(f0+c)*OBS_D; }
      __shared__ float lx[32][257];
      const int r0 = threadIdx.x>>3;
      const int kk = (threadIdx.x&7)<<2;
      for (int kc=0; kc<OBS_D; kc+=32){
        __syncthreads();
        #pragma unroll
        for (int rr=0; rr<256; rr+=32){
          const float4 v = *(const float4*)(obs + ((size_t)te*BATCH + (r0+rr))*OBS_D + kc + kk);
          lx[kk+0][r0+rr]=v.x; lx[kk+1][r0+rr]=v.y; lx[kk+2][r0+rr]=v.z; lx[kk+3][r0+rr]=v.w;
        }
        __syncthreads();
        #pragma unroll 4
        for (int k2=0;k2<32;++k2){
          const float xv = lx[k2][b];
          #pragma unroll
          for (int c=0;c<8;++c) acc[c] = fmaf(xv, wrow[c][kc+k2], acc[c]);
        }
      }
      #pragma unroll
      for (int c=0;c<8;++c) xs[(size_t)(f0+c)*BATCH + b] = fmaxf(acc[c], 0.0f);
    } else {
      const float r = reward[te*BATCH + b];
      xs[(size_t)FEATD*BATCH + b] = fminf(fmaxf(r, -1.0f), 1.0f);
      const int la = lastAct[te*BATCH + b];
      #pragma unroll
      for (int a2=0; a2<NACT; ++a2)
        xs[(size_t)(FEATD+1+a2)*BATCH + b] = (a2==la) ? 1.0f : 0.0f;
    }
  } else {                               /* head + sampling @ t-2 */
    const int s = t - 2;
    if (s < 0 || s > 255) return;
    const float* hsrc = h1 + (size_t)(s&1)*HB;
    float acc[16];
    #pragma unroll
    for (int c=0;c<16;++c) acc[c]=alw[DHB+c];
    const float* hb = hsrc + b;
    #pragma unroll 4
    for (int k=0;k<HDIM;++k){
      const float hv = hb[(size_t)k*BATCH];
      #pragma unroll
      for (int c=0;c<16;++c) acc[c] = fmaf(hv, alw[DHW + (size_t)c*HDIM + k], acc[c]);
    }
    const int row = s*BATCH + b;
    #pragma unroll
    for (int c=0;c<15;++c) out[OUT_POL + (size_t)row*NACT + c] = acc[c];
    out[OUT_BASE + row] = acc[15];
    double best = -1.0e300; int bi = 0;
    #pragma unroll
    for (int a2=0; a2<NACT; ++a2){
      const double v = (double)acc[a2] + gumbel_for((uint32_t)(row*NACT + a2));
      if (v > best){ best = v; bi = a2; }
    }
    out[OUT_ACT + row] = (float)bi;
  }
}

__global__ void finalize_kernel(const float* __restrict__ ws, float* __restrict__ out){
  int i = blockIdx.x*256 + threadIdx.x;
  if (i >= 2*HB) return;
  const int l = i / HB;
  const int r = i % HB;
  const int bq = r / HDIM;
  const int j  = r % HDIM;
  const float* hf = ws + (l==0 ? FH0 : FH1) + HB;   /* step-255 parity = 1 */
  const float* cf = ws + (l==0 ? FC0 : FC1);
  out[OUT_H + i] = hf[(size_t)j*BATCH + bq];
  out[OUT_C + i] = cf[(size_t)j*BATCH + bq];
}

extern "C" void kernel_launch(void* const* d_in, const int* in_sizes, int n_in,
                              void* d_out, int out_size, void* d_ws, size_t ws_size,
                              hipStream_t stream) {
  const float* obs     = (const float*)d_in[0];
  const int*   lastAct = (const int*)  d_in[1];
  const float* reward  = (const float*)d_in[2];
  const void*  term    =               d_in[3];
  const float* Wenc    = (const float*)d_in[4];
  const float* benc    = (const float*)d_in[5];
  const float* wih0    = (const float*)d_in[6];
  const float* whh0    = (const float*)d_in[7];
  const float* bih0    = (const float*)d_in[8];
  const float* bhh0    = (const float*)d_in[9];
  const float* wih1    = (const float*)d_in[10];
  const float* whh1    = (const float*)d_in[11];
  const float* bih1    = (const float*)d_in[12];
  const float* bhh1    = (const float*)d_in[13];
  const float* Wpol    = (const float*)d_in[14];
  const float* bpol    = (const float*)d_in[15];
  const float* Wbase   = (const float*)d_in[16];
  const float* bbase   = (const float*)d_in[17];
  float*  ws   = (float*)d_ws;
  int*    flag = (int*)(ws + OFF_FLAG);
  float*  alw  = (float*)((char*)d_ws + ALW_BYTES);
  float*  out  = (float*)d_out;

  /* zero h/c state (6*HB floats at FH0) every call */
  {
    const int nz = 6*HB;
    zero_kernel<<<(nz+255)/256, 256, 0, stream>>>(ws + FH0, nz);
  }
  detect_term_kernel<<<1, 256, 0, stream>>>(term, flag);
  nd_kernel<<<(TSTEPS*BATCH+255)/256, 256, 0, stream>>>(term, flag, ws + OFF_ND);
  prep_small_kernel<<<(DALW_N+255)/256, 256, 0, stream>>>(alw,
      bih0, bhh0, bih1, bhh1, benc, Wpol, bpol, Wbase, bbase);

  for (int t = -2; t <= 257; ++t) {
    step_kernel<<<594, 256, 0, stream>>>(
      obs, lastAct, reward,
      Wenc, wih0, whh0, wih1, whh1,
      ws, alw, out, t);
  }
  finalize_kernel<<<(2*HB+255)/256, 256, 0, stream>>>(ws, out);
}